// Round 15
// baseline (120.939 us; speedup 1.0000x reference)
//
#include <hip/hip_runtime.h>

// Problem constants (from reference setup_inputs)
#define BB    16
#define NN    8192
#define DD    128
#define MM    2048
#define TOPKK 512
#define TT    (BB*MM)     // 32768
#define BNN   (BB*NN)     // 131072
#define WINS  (BB*TOPKK)  // 8192
#define CAP   24          // max rows/segment slotted (Poisson(4): P(>=24) ~ 1e-12)
#define OVCAP 4096

// ---------------- workspace layout (bytes) ----------------
#define WS_COUNTS  0           // int[TT]        131072   } one memset
#define WS_AGG     131072      // double[TT]     262144   }
#define WS_OVC     393216      // int[16]        64       }
#define WS_W32     393280      // float[B*384]   24576
#define WS_C       417856      // double[B]      128
#define WS_IDX     417984      // int[WINS]      32768
#define WS_ATT     450752      // double[BNN]    1048576
#define WS_LIST2   1499328     // int[TT*CAP]    3145728
#define WS_OVBUF   4645056     // int2[OVCAP]    32768

// Per-batch precompute: query_b, alpha_b, w_b = Wa @ alpha_b (f32 out), c_b.
__global__ __launch_bounds__(128) void k_prep(const float* __restrict__ q_head,
                                              const float* __restrict__ q_rel,
                                              const float* __restrict__ q_time,
                                              const float* __restrict__ Wq,
                                              const float* __restrict__ bq,
                                              const float* __restrict__ Wa,
                                              const float* __restrict__ ba,
                                              const float* __restrict__ Watt,
                                              const float* __restrict__ batt,
                                              float* __restrict__ w32_out,  // B*384 f32
                                              double* __restrict__ c_out) { // B
    int b = blockIdx.x;
    int d = threadIdx.x; // 0..127
    __shared__ double x_s[3*DD];
    __shared__ double alpha_s[DD];
    __shared__ double kpart[DD];
    x_s[d]        = (double)q_head[b*DD + d];
    x_s[DD + d]   = (double)q_rel [b*DD + d];
    x_s[2*DD + d] = (double)q_time[b*DD + d];
    __syncthreads();

    double acc = (double)bq[d];
    for (int k = 0; k < 3*DD; ++k) acc += x_s[k] * (double)Wq[k*DD + d];

    double W1 = (double)Watt[d];
    double W2 = (double)Watt[DD + d];
    double W3 = (double)Watt[2*DD + d];
    double a  = W1 * acc - W2 + W3;
    alpha_s[d] = a;
    kpart[d]   = acc * (W2 + W3) + (double)ba[d] * a;
    __syncthreads();

    for (int kk = d; kk < 3*DD; kk += DD) {
        double s = 0.0;
        for (int dd = 0; dd < DD; ++dd) s += (double)Wa[kk*DD + dd] * alpha_s[dd];
        w32_out[b*3*DD + kk] = (float)s;   // per-batch f32 rounding (validated R4+)
    }
    if (d == 0) {
        double K = (double)batt[0];
        for (int dd = 0; dd < DD; ++dd) K += kpart[dd];
        c_out[b] = K;
    }
}

__device__ __forceinline__ double dot4d(const float4 a, const float4 w) {
    return (double)a.x*(double)w.x + (double)a.y*(double)w.y
         + (double)a.z*(double)w.z + (double)a.w*(double)w.w;
}

// Non-temporal float4 load via clang native vector (nt bit: no LLC allocation)
typedef float nf4 __attribute__((ext_vector_type(4)));
__device__ __forceinline__ float4 ldnt4(const float* p) {
    nf4 v = __builtin_nontemporal_load((const nf4*)p);
    return make_float4(v.x, v.y, v.z, v.w);
}

// ---------------- Phase A: one-shot streaming (R8/R11 measured-best) ----
// One row per 32-lane half-wave, float4/lane. f64 dot/butterfly/exp for
// ranking accuracy; parity exp dedup; fused agg_att atomic + capped CSR fill.
// NT loads on t_n (never re-read) and r_n: keeps tm_n+hidden L3-resident and
// turns the HBM miss stream sequential instead of interleaved-with-hits.
__global__ __launch_bounds__(256) void k_att(const float* __restrict__ r_n,
                                             const float* __restrict__ t_n,
                                             const float* __restrict__ tm_n,
                                             const float* __restrict__ hidden,
                                             const float* __restrict__ w32_all,
                                             const double* __restrict__ c_all,
                                             const float* __restrict__ Wrule,
                                             const float* __restrict__ brule,
                                             const int* __restrict__ tail_index,
                                             double* __restrict__ attArr,
                                             double* __restrict__ agg_att,
                                             int* __restrict__ counts,
                                             int* __restrict__ list2,
                                             int* __restrict__ ovCnt,
                                             int2* __restrict__ ovBuf) {
    const int wave = threadIdx.x >> 6;
    const int lane = threadIdx.x & 63;
    const int half = lane >> 5;
    const int sl   = lane & 31;
    const int d0   = 4 * sl;
    const int row  = (blockIdx.x * 4 + wave) * 2 + half;
    const int b    = row >> 13;

    const float* w = w32_all + b * 3 * DD;
    const float4 w0 = *(const float4*)(w + d0);
    const float4 w1 = *(const float4*)(w + DD + d0);
    const float4 w2 = *(const float4*)(w + 2*DD + d0);
    const float4 wr = *(const float4*)(Wrule + d0);
    const double cb = c_all[b];
    const double br = (double)brule[0];

    long long base = (long long)row * DD + d0;
    float4 rv = ldnt4(r_n + base);               // nt
    float4 tv = ldnt4(t_n + base);               // nt (never re-read)
    float4 mv = *(const float4*)(tm_n   + base); // cached
    float4 hv = *(const float4*)(hidden + base); // cached

    double z1 = dot4d(rv, w0) + dot4d(tv, w1) + dot4d(mv, w2);
    double z2 = dot4d(hv, wr);
    #pragma unroll
    for (int o = 16; o > 0; o >>= 1) {
        z1 += __shfl_xor(z1, o);
        z2 += __shfl_xor(z2, o);
    }
    // parity exp dedup: even lanes exp(-(z1+cb)), odd lanes exp(-(z2+br))
    double x  = (lane & 1) ? (z2 + br) : (z1 + cb);
    double ex = exp(-x);
    double exo = __shfl_xor(ex, 1);
    double att = 0.5 * (2.0 + ex + exo) / ((1.0 + ex) * (1.0 + exo));

    if (sl == 0) {
        attArr[row] = att;
        int t = tail_index[row];
        unsafeAtomicAdd(&agg_att[t], att);
        int c = atomicAdd(&counts[t], 1);
        if (c < CAP) list2[t*CAP + c] = row;
        else { int p = atomicAdd(ovCnt, 1); if (p < OVCAP) ovBuf[p] = make_int2(t, row); }
    }
}

// ---------------- exact top-k by rank selection (4 threads per candidate) ----
// rank(i) = #{j : v[j]>v[i] or (v[j]==v[i] and j<i)}; rank<K -> position rank.
// Identical tie semantics to sort-by-(value desc, index asc).
__global__ __launch_bounds__(512) void k_rank(const double* __restrict__ agg_att,
                                              const int* __restrict__ tail_nodes,
                                              int* __restrict__ idx_out,
                                              float* __restrict__ out_nodes) {
    const int b     = blockIdx.x >> 4;
    const int chunk = blockIdx.x & 15;
    __shared__ double v[MM];
    for (int i = threadIdx.x; i < MM; i += 512) v[i] = agg_att[b*MM + i];
    __syncthreads();
    const int iloc = threadIdx.x >> 2;        // 0..127
    const int part = threadIdx.x & 3;         // 0..3
    const int i    = chunk * 128 + iloc;
    const double vi = v[i];
    const int j0 = part * 512;
    int rank = 0;
    #pragma unroll 8
    for (int jj = 0; jj < 256; ++jj) {
        double2 p = *(const double2*)(&v[j0 + 2*jj]);
        int ja = j0 + 2*jj;
        rank += (p.x > vi || (p.x == vi && ja     < i)) ? 1 : 0;
        rank += (p.y > vi || (p.y == vi && ja + 1 < i)) ? 1 : 0;
    }
    rank += __shfl_xor(rank, 1);
    rank += __shfl_xor(rank, 2);
    if (part == 0 && rank < TOPKK) {
        int t = b*MM + i;
        idx_out[b*TOPKK + rank] = t;
        out_nodes[(b*TOPKK + rank)*2 + 0] = (float)tail_nodes[t*3 + 1];
        out_nodes[(b*TOPKK + rank)*2 + 1] = (float)tail_nodes[t*3 + 2];
    }
}

// ---------------- Fused Phase C + epilogue (winners only) ----------------
// 512 threads = 16 half-waves; ONE winner per half-wave.
__global__ __launch_bounds__(512) void k_aggWO(const float* __restrict__ r_n,
                                               const float* __restrict__ tm_n,
                                               const float* __restrict__ hidden,
                                               const float* __restrict__ q_head,
                                               const float* __restrict__ tail_emd,
                                               const int* __restrict__ counts,
                                               const int* __restrict__ list2,
                                               const int* __restrict__ ovCnt,
                                               const int2* __restrict__ ovBuf,
                                               const double* __restrict__ attArr,
                                               const int* __restrict__ idx_ws,
                                               const float* __restrict__ Wout,
                                               const float* __restrict__ bout,
                                               float* __restrict__ out_emd,
                                               float* __restrict__ out_hid) {
    __shared__ float a_s[16][DD];   // 8KB
    const int tid = threadIdx.x;
    const int hw  = tid >> 5;       // 0..15
    const int sl  = tid & 31;
    const int d0  = 4 * sl;
    const int w0i = blockIdx.x * 16;

    {
        const int wi = w0i + hw;
        const int t  = idx_ws[wi];
        const int b  = t >> 11;
        const float4 qh = *(const float4*)(q_head + b*DD + d0);
        const int cnt = counts[t];
        const int n   = cnt < CAP ? cnt : CAP;

        float p0 = 0.f, p1 = 0.f, p2 = 0.f, p3 = 0.f;
        float h0 = 0.f, h1 = 0.f, h2 = 0.f, h3 = 0.f;
        double asum = 0.0;
        for (int e = 0; e < n; ++e) {
            int row = list2[t*CAP + e];
            long long base = (long long)row * DD + d0;
            float4 rv = *(const float4*)(r_n    + base);
            float4 mv = *(const float4*)(tm_n   + base);
            float4 hv = *(const float4*)(hidden + base);
            double attd = attArr[row];
            float  att  = (float)attd;
            p0 += att * (rv.x + mv.x); p1 += att * (rv.y + mv.y);
            p2 += att * (rv.z + mv.z); p3 += att * (rv.w + mv.w);
            h0 += hv.x; h1 += hv.y; h2 += hv.z; h3 += hv.w;
            asum += attd;
        }
        if (cnt > CAP) {  // essentially never; correctness fallback
            int m = *ovCnt; if (m > OVCAP) m = OVCAP;
            for (int k2 = 0; k2 < m; ++k2) {
                int2 pr = ovBuf[k2];
                if (pr.x == t) {
                    int row = pr.y;
                    long long base = (long long)row * DD + d0;
                    float4 rv = *(const float4*)(r_n    + base);
                    float4 mv = *(const float4*)(tm_n   + base);
                    float4 hv = *(const float4*)(hidden + base);
                    double attd = attArr[row];
                    float  att  = (float)attd;
                    p0 += att * (rv.x + mv.x); p1 += att * (rv.y + mv.y);
                    p2 += att * (rv.z + mv.z); p3 += att * (rv.w + mv.w);
                    h0 += hv.x; h1 += hv.y; h2 += hv.z; h3 += hv.w;
                    asum += attd;
                }
            }
        }
        float A = (float)asum;
        long long ot = (long long)t * DD + d0;
        float4 te = *(const float4*)(tail_emd + ot);
        float4 ta;
        ta.x = te.x + A*qh.x + p0; ta.y = te.y + A*qh.y + p1;
        ta.z = te.z + A*qh.z + p2; ta.w = te.w + A*qh.w + p3;
        *(float4*)(&a_s[hw][d0]) = ta;
        float4 nh; nh.x = h0; nh.y = h1; nh.z = h2; nh.w = h3;
        *(float4*)(out_hid + (long long)wi * DD + d0) = nh;
    }
    __syncthreads();

    // GEMM phase: 512 threads = 4 row-quads x 128 columns
    const int c  = tid & 127;
    const int j0 = (tid >> 7) * 4;
    float acc[4];
    const float bc = bout[c];
    #pragma unroll
    for (int j = 0; j < 4; ++j) acc[j] = bc;
    for (int d = 0; d < DD; ++d) {
        float wvv = Wout[d*DD + c];
        #pragma unroll
        for (int j = 0; j < 4; ++j)
            acc[j] = fmaf(a_s[j0 + j][d], wvv, acc[j]);
    }
    #pragma unroll
    for (int j = 0; j < 4; ++j)
        out_emd[(long long)(w0i + j0 + j) * DD + c] = acc[j];
}

extern "C" void kernel_launch(void* const* d_in, const int* in_sizes, int n_in,
                              void* d_out, int out_size, void* d_ws, size_t ws_size,
                              hipStream_t stream) {
    const float* q_head   = (const float*)d_in[0];
    const float* q_rel    = (const float*)d_in[1];
    const float* q_time   = (const float*)d_in[2];
    const float* r_n      = (const float*)d_in[3];
    const float* t_n      = (const float*)d_in[4];
    const float* tm_n     = (const float*)d_in[5];
    const float* hidden   = (const float*)d_in[6];
    const float* tail_emd = (const float*)d_in[7];
    const int*   tail_index = (const int*)d_in[8];
    const int*   tail_nodes = (const int*)d_in[9];
    const float* Wq   = (const float*)d_in[10];
    const float* bq   = (const float*)d_in[11];
    const float* Wa   = (const float*)d_in[12];
    const float* ba   = (const float*)d_in[13];
    const float* Watt = (const float*)d_in[14];
    const float* batt = (const float*)d_in[15];
    const float* Wrule = (const float*)d_in[16];
    const float* brule = (const float*)d_in[17];
    const float* Wout = (const float*)d_in[18];
    const float* bout = (const float*)d_in[19];

    char* ws = (char*)d_ws;
    int*    counts  = (int*)   (ws + WS_COUNTS);
    double* agg_att = (double*)(ws + WS_AGG);
    int*    ovCnt   = (int*)   (ws + WS_OVC);
    float*  w32     = (float*) (ws + WS_W32);
    double* c_all   = (double*)(ws + WS_C);
    int*    idx_ws  = (int*)   (ws + WS_IDX);
    double* attArr  = (double*)(ws + WS_ATT);
    int*    list2   = (int*)   (ws + WS_LIST2);
    int2*   ovBuf   = (int2*)  (ws + WS_OVBUF);

    float* out       = (float*)d_out;
    float* out_nodes = out;                      // B*TOPK*2
    float* out_emd   = out + BB*TOPKK*2;         // B*TOPK*D
    float* out_hid   = out_emd + BB*TOPKK*DD;    // B*TOPK*D

    // counts + agg_att + ovCnt adjacent: single memset
    (void)hipMemsetAsync(counts, 0, 393280, stream);
    hipLaunchKernelGGL(k_prep, dim3(BB), dim3(DD), 0, stream,
                       q_head, q_rel, q_time, Wq, bq, Wa, ba, Watt, batt,
                       w32, c_all);
    hipLaunchKernelGGL(k_att, dim3(BNN/8), dim3(256), 0, stream,
                       r_n, t_n, tm_n, hidden, w32, c_all, Wrule, brule,
                       tail_index, attArr, agg_att, counts, list2, ovCnt, ovBuf);
    hipLaunchKernelGGL(k_rank, dim3(BB*16), dim3(512), 0, stream,
                       agg_att, tail_nodes, idx_ws, out_nodes);
    hipLaunchKernelGGL(k_aggWO, dim3(WINS/16), dim3(512), 0, stream,
                       r_n, tm_n, hidden, q_head, tail_emd,
                       counts, list2, ovCnt, ovBuf, attArr, idx_ws,
                       Wout, bout, out_emd, out_hid);
}

// Round 16
// 119.655 us; speedup vs baseline: 1.0107x; 1.0107x over previous
//
#include <hip/hip_runtime.h>

// Problem constants (from reference setup_inputs)
#define BB    16
#define NN    8192
#define DD    128
#define MM    2048
#define TOPKK 512
#define TT    (BB*MM)     // 32768
#define BNN   (BB*NN)     // 131072
#define WINS  (BB*TOPKK)  // 8192
#define CAP   24          // max rows/segment slotted (Poisson(4): P(>=24) ~ 1e-12)
#define OVCAP 4096

// ---------------- workspace layout (bytes) ----------------
#define WS_COUNTS  0           // int[TT]        131072   } one memset
#define WS_AGG     131072      // double[TT]     262144   }
#define WS_OVC     393216      // int[16]        64       }
#define WS_W32     393280      // float[B*384]   24576
#define WS_C       417856      // double[B]      128
#define WS_IDX     417984      // int[WINS]      32768
#define WS_ATT     450752      // double[BNN]    1048576
#define WS_LIST2   1499328     // int[TT*CAP]    3145728
#define WS_OVBUF   4645056     // int2[OVCAP]    32768

// Per-batch precompute: query_b, alpha_b, w_b = Wa @ alpha_b (f32 out), c_b.
__global__ __launch_bounds__(128) void k_prep(const float* __restrict__ q_head,
                                              const float* __restrict__ q_rel,
                                              const float* __restrict__ q_time,
                                              const float* __restrict__ Wq,
                                              const float* __restrict__ bq,
                                              const float* __restrict__ Wa,
                                              const float* __restrict__ ba,
                                              const float* __restrict__ Watt,
                                              const float* __restrict__ batt,
                                              float* __restrict__ w32_out,  // B*384 f32
                                              double* __restrict__ c_out) { // B
    int b = blockIdx.x;
    int d = threadIdx.x; // 0..127
    __shared__ double x_s[3*DD];
    __shared__ double alpha_s[DD];
    __shared__ double kpart[DD];
    x_s[d]        = (double)q_head[b*DD + d];
    x_s[DD + d]   = (double)q_rel [b*DD + d];
    x_s[2*DD + d] = (double)q_time[b*DD + d];
    __syncthreads();

    double acc = (double)bq[d];
    for (int k = 0; k < 3*DD; ++k) acc += x_s[k] * (double)Wq[k*DD + d];

    double W1 = (double)Watt[d];
    double W2 = (double)Watt[DD + d];
    double W3 = (double)Watt[2*DD + d];
    double a  = W1 * acc - W2 + W3;
    alpha_s[d] = a;
    kpart[d]   = acc * (W2 + W3) + (double)ba[d] * a;
    __syncthreads();

    for (int kk = d; kk < 3*DD; kk += DD) {
        double s = 0.0;
        for (int dd = 0; dd < DD; ++dd) s += (double)Wa[kk*DD + dd] * alpha_s[dd];
        w32_out[b*3*DD + kk] = (float)s;   // per-batch f32 rounding (validated R4+)
    }
    if (d == 0) {
        double K = (double)batt[0];
        for (int dd = 0; dd < DD; ++dd) K += kpart[dd];
        c_out[b] = K;
    }
}

__device__ __forceinline__ double dot4d(const float4 a, const float4 w) {
    return (double)a.x*(double)w.x + (double)a.y*(double)w.y
         + (double)a.z*(double)w.z + (double)a.w*(double)w.w;
}

// Non-temporal float4 load via clang native vector (nt bit: no LLC allocation)
typedef float nf4 __attribute__((ext_vector_type(4)));
__device__ __forceinline__ float4 ldnt4(const float* p) {
    nf4 v = __builtin_nontemporal_load((const nf4*)p);
    return make_float4(v.x, v.y, v.z, v.w);
}

// ---------------- Phase A: one-shot streaming (R8/R11 measured-best) ----
// One row per 32-lane half-wave, float4/lane. f64 dot/butterfly/exp for
// ranking accuracy; parity exp dedup; fused agg_att atomic + capped CSR fill.
// NT load on t_n ONLY: it is the sole stream-once array (k_aggWO re-reads
// r_n/tm_n/hidden). Shrinks the LLC working set 256->192MB so the re-read
// arrays stay resident for the gather phase (R15 lesson: nt on r_n evicted
// it and k_aggWO's gathers went to HBM).
__global__ __launch_bounds__(256) void k_att(const float* __restrict__ r_n,
                                             const float* __restrict__ t_n,
                                             const float* __restrict__ tm_n,
                                             const float* __restrict__ hidden,
                                             const float* __restrict__ w32_all,
                                             const double* __restrict__ c_all,
                                             const float* __restrict__ Wrule,
                                             const float* __restrict__ brule,
                                             const int* __restrict__ tail_index,
                                             double* __restrict__ attArr,
                                             double* __restrict__ agg_att,
                                             int* __restrict__ counts,
                                             int* __restrict__ list2,
                                             int* __restrict__ ovCnt,
                                             int2* __restrict__ ovBuf) {
    const int wave = threadIdx.x >> 6;
    const int lane = threadIdx.x & 63;
    const int half = lane >> 5;
    const int sl   = lane & 31;
    const int d0   = 4 * sl;
    const int row  = (blockIdx.x * 4 + wave) * 2 + half;
    const int b    = row >> 13;

    const float* w = w32_all + b * 3 * DD;
    const float4 w0 = *(const float4*)(w + d0);
    const float4 w1 = *(const float4*)(w + DD + d0);
    const float4 w2 = *(const float4*)(w + 2*DD + d0);
    const float4 wr = *(const float4*)(Wrule + d0);
    const double cb = c_all[b];
    const double br = (double)brule[0];

    long long base = (long long)row * DD + d0;
    float4 rv = *(const float4*)(r_n    + base); // cached (re-read by k_aggWO)
    float4 tv = ldnt4(t_n + base);               // nt (never re-read)
    float4 mv = *(const float4*)(tm_n   + base); // cached
    float4 hv = *(const float4*)(hidden + base); // cached

    double z1 = dot4d(rv, w0) + dot4d(tv, w1) + dot4d(mv, w2);
    double z2 = dot4d(hv, wr);
    #pragma unroll
    for (int o = 16; o > 0; o >>= 1) {
        z1 += __shfl_xor(z1, o);
        z2 += __shfl_xor(z2, o);
    }
    // parity exp dedup: even lanes exp(-(z1+cb)), odd lanes exp(-(z2+br))
    double x  = (lane & 1) ? (z2 + br) : (z1 + cb);
    double ex = exp(-x);
    double exo = __shfl_xor(ex, 1);
    double att = 0.5 * (2.0 + ex + exo) / ((1.0 + ex) * (1.0 + exo));

    if (sl == 0) {
        attArr[row] = att;
        int t = tail_index[row];
        unsafeAtomicAdd(&agg_att[t], att);
        int c = atomicAdd(&counts[t], 1);
        if (c < CAP) list2[t*CAP + c] = row;
        else { int p = atomicAdd(ovCnt, 1); if (p < OVCAP) ovBuf[p] = make_int2(t, row); }
    }
}

// ---------------- exact top-k by rank selection (4 threads per candidate) ----
// rank(i) = #{j : v[j]>v[i] or (v[j]==v[i] and j<i)}; rank<K -> position rank.
// Identical tie semantics to sort-by-(value desc, index asc).
__global__ __launch_bounds__(512) void k_rank(const double* __restrict__ agg_att,
                                              const int* __restrict__ tail_nodes,
                                              int* __restrict__ idx_out,
                                              float* __restrict__ out_nodes) {
    const int b     = blockIdx.x >> 4;
    const int chunk = blockIdx.x & 15;
    __shared__ double v[MM];
    for (int i = threadIdx.x; i < MM; i += 512) v[i] = agg_att[b*MM + i];
    __syncthreads();
    const int iloc = threadIdx.x >> 2;        // 0..127
    const int part = threadIdx.x & 3;         // 0..3
    const int i    = chunk * 128 + iloc;
    const double vi = v[i];
    const int j0 = part * 512;
    int rank = 0;
    #pragma unroll 8
    for (int jj = 0; jj < 256; ++jj) {
        double2 p = *(const double2*)(&v[j0 + 2*jj]);
        int ja = j0 + 2*jj;
        rank += (p.x > vi || (p.x == vi && ja     < i)) ? 1 : 0;
        rank += (p.y > vi || (p.y == vi && ja + 1 < i)) ? 1 : 0;
    }
    rank += __shfl_xor(rank, 1);
    rank += __shfl_xor(rank, 2);
    if (part == 0 && rank < TOPKK) {
        int t = b*MM + i;
        idx_out[b*TOPKK + rank] = t;
        out_nodes[(b*TOPKK + rank)*2 + 0] = (float)tail_nodes[t*3 + 1];
        out_nodes[(b*TOPKK + rank)*2 + 1] = (float)tail_nodes[t*3 + 2];
    }
}

// ---------------- Fused Phase C + epilogue (winners only) ----------------
// 512 threads = 16 half-waves; ONE winner per half-wave.
__global__ __launch_bounds__(512) void k_aggWO(const float* __restrict__ r_n,
                                               const float* __restrict__ tm_n,
                                               const float* __restrict__ hidden,
                                               const float* __restrict__ q_head,
                                               const float* __restrict__ tail_emd,
                                               const int* __restrict__ counts,
                                               const int* __restrict__ list2,
                                               const int* __restrict__ ovCnt,
                                               const int2* __restrict__ ovBuf,
                                               const double* __restrict__ attArr,
                                               const int* __restrict__ idx_ws,
                                               const float* __restrict__ Wout,
                                               const float* __restrict__ bout,
                                               float* __restrict__ out_emd,
                                               float* __restrict__ out_hid) {
    __shared__ float a_s[16][DD];   // 8KB
    const int tid = threadIdx.x;
    const int hw  = tid >> 5;       // 0..15
    const int sl  = tid & 31;
    const int d0  = 4 * sl;
    const int w0i = blockIdx.x * 16;

    {
        const int wi = w0i + hw;
        const int t  = idx_ws[wi];
        const int b  = t >> 11;
        const float4 qh = *(const float4*)(q_head + b*DD + d0);
        const int cnt = counts[t];
        const int n   = cnt < CAP ? cnt : CAP;

        float p0 = 0.f, p1 = 0.f, p2 = 0.f, p3 = 0.f;
        float h0 = 0.f, h1 = 0.f, h2 = 0.f, h3 = 0.f;
        double asum = 0.0;
        for (int e = 0; e < n; ++e) {
            int row = list2[t*CAP + e];
            long long base = (long long)row * DD + d0;
            float4 rv = *(const float4*)(r_n    + base);
            float4 mv = *(const float4*)(tm_n   + base);
            float4 hv = *(const float4*)(hidden + base);
            double attd = attArr[row];
            float  att  = (float)attd;
            p0 += att * (rv.x + mv.x); p1 += att * (rv.y + mv.y);
            p2 += att * (rv.z + mv.z); p3 += att * (rv.w + mv.w);
            h0 += hv.x; h1 += hv.y; h2 += hv.z; h3 += hv.w;
            asum += attd;
        }
        if (cnt > CAP) {  // essentially never; correctness fallback
            int m = *ovCnt; if (m > OVCAP) m = OVCAP;
            for (int k2 = 0; k2 < m; ++k2) {
                int2 pr = ovBuf[k2];
                if (pr.x == t) {
                    int row = pr.y;
                    long long base = (long long)row * DD + d0;
                    float4 rv = *(const float4*)(r_n    + base);
                    float4 mv = *(const float4*)(tm_n   + base);
                    float4 hv = *(const float4*)(hidden + base);
                    double attd = attArr[row];
                    float  att  = (float)attd;
                    p0 += att * (rv.x + mv.x); p1 += att * (rv.y + mv.y);
                    p2 += att * (rv.z + mv.z); p3 += att * (rv.w + mv.w);
                    h0 += hv.x; h1 += hv.y; h2 += hv.z; h3 += hv.w;
                    asum += attd;
                }
            }
        }
        float A = (float)asum;
        long long ot = (long long)t * DD + d0;
        float4 te = *(const float4*)(tail_emd + ot);
        float4 ta;
        ta.x = te.x + A*qh.x + p0; ta.y = te.y + A*qh.y + p1;
        ta.z = te.z + A*qh.z + p2; ta.w = te.w + A*qh.w + p3;
        *(float4*)(&a_s[hw][d0]) = ta;
        float4 nh; nh.x = h0; nh.y = h1; nh.z = h2; nh.w = h3;
        *(float4*)(out_hid + (long long)wi * DD + d0) = nh;
    }
    __syncthreads();

    // GEMM phase: 512 threads = 4 row-quads x 128 columns
    const int c  = tid & 127;
    const int j0 = (tid >> 7) * 4;
    float acc[4];
    const float bc = bout[c];
    #pragma unroll
    for (int j = 0; j < 4; ++j) acc[j] = bc;
    for (int d = 0; d < DD; ++d) {
        float wvv = Wout[d*DD + c];
        #pragma unroll
        for (int j = 0; j < 4; ++j)
            acc[j] = fmaf(a_s[j0 + j][d], wvv, acc[j]);
    }
    #pragma unroll
    for (int j = 0; j < 4; ++j)
        out_emd[(long long)(w0i + j0 + j) * DD + c] = acc[j];
}

extern "C" void kernel_launch(void* const* d_in, const int* in_sizes, int n_in,
                              void* d_out, int out_size, void* d_ws, size_t ws_size,
                              hipStream_t stream) {
    const float* q_head   = (const float*)d_in[0];
    const float* q_rel    = (const float*)d_in[1];
    const float* q_time   = (const float*)d_in[2];
    const float* r_n      = (const float*)d_in[3];
    const float* t_n      = (const float*)d_in[4];
    const float* tm_n     = (const float*)d_in[5];
    const float* hidden   = (const float*)d_in[6];
    const float* tail_emd = (const float*)d_in[7];
    const int*   tail_index = (const int*)d_in[8];
    const int*   tail_nodes = (const int*)d_in[9];
    const float* Wq   = (const float*)d_in[10];
    const float* bq   = (const float*)d_in[11];
    const float* Wa   = (const float*)d_in[12];
    const float* ba   = (const float*)d_in[13];
    const float* Watt = (const float*)d_in[14];
    const float* batt = (const float*)d_in[15];
    const float* Wrule = (const float*)d_in[16];
    const float* brule = (const float*)d_in[17];
    const float* Wout = (const float*)d_in[18];
    const float* bout = (const float*)d_in[19];

    char* ws = (char*)d_ws;
    int*    counts  = (int*)   (ws + WS_COUNTS);
    double* agg_att = (double*)(ws + WS_AGG);
    int*    ovCnt   = (int*)   (ws + WS_OVC);
    float*  w32     = (float*) (ws + WS_W32);
    double* c_all   = (double*)(ws + WS_C);
    int*    idx_ws  = (int*)   (ws + WS_IDX);
    double* attArr  = (double*)(ws + WS_ATT);
    int*    list2   = (int*)   (ws + WS_LIST2);
    int2*   ovBuf   = (int2*)  (ws + WS_OVBUF);

    float* out       = (float*)d_out;
    float* out_nodes = out;                      // B*TOPK*2
    float* out_emd   = out + BB*TOPKK*2;         // B*TOPK*D
    float* out_hid   = out_emd + BB*TOPKK*DD;    // B*TOPK*D

    // counts + agg_att + ovCnt adjacent: single memset
    (void)hipMemsetAsync(counts, 0, 393280, stream);
    hipLaunchKernelGGL(k_prep, dim3(BB), dim3(DD), 0, stream,
                       q_head, q_rel, q_time, Wq, bq, Wa, ba, Watt, batt,
                       w32, c_all);
    hipLaunchKernelGGL(k_att, dim3(BNN/8), dim3(256), 0, stream,
                       r_n, t_n, tm_n, hidden, w32, c_all, Wrule, brule,
                       tail_index, attArr, agg_att, counts, list2, ovCnt, ovBuf);
    hipLaunchKernelGGL(k_rank, dim3(BB*16), dim3(512), 0, stream,
                       agg_att, tail_nodes, idx_ws, out_nodes);
    hipLaunchKernelGGL(k_aggWO, dim3(WINS/16), dim3(512), 0, stream,
                       r_n, tm_n, hidden, q_head, tail_emd,
                       counts, list2, ovCnt, ovBuf, attArr, idx_ws,
                       Wout, bout, out_emd, out_hid);
}